// Round 1
// baseline (772.429 us; speedup 1.0000x reference)
//
#include <hip/hip_runtime.h>
#include <math.h>

#define NN 8192
#define FIN 128
#define HD 32
#define NC 10
#define NE 262144
#define EPSBN 1e-5f

typedef short short8 __attribute__((ext_vector_type(8)));
typedef float f32x4 __attribute__((ext_vector_type(4)));

__device__ __forceinline__ float bf2f(unsigned short b) {
  unsigned int u = ((unsigned int)b) << 16;
  float f;
  __builtin_memcpy(&f, &u, 4);
  return f;
}
__device__ __forceinline__ unsigned short f2bf(float f) {
  unsigned int u;
  __builtin_memcpy(&u, &f, 4);
  u = u + 0x7fffu + ((u >> 16) & 1u);
  return (unsigned short)(u >> 16);
}
__device__ __forceinline__ short8 ld_bf8(const unsigned short* p) {
  uint4 u = *(const uint4*)p;
  return __builtin_bit_cast(short8, u);
}
__device__ __forceinline__ float ldin(const void* p, int i, int isf) {
  if (isf) return ((const float*)p)[i];
  return bf2f(((const unsigned short*)p)[i]);
}

// ---------- dtype detection: even-indexed shorts of b (f32 low-mantissa halves are random) ----
__global__ void detect_k(const void* __restrict__ b, int* __restrict__ flag) {
  const unsigned short* p = (const unsigned short*)b;
  int t = threadIdx.x;
  unsigned short s = p[2 * t];
  int e = (s >> 7) & 0xFF;
  int hit = (e >= 110 && e <= 135) ? 1 : 0;
  __shared__ int cnt[256];
  cnt[t] = hit;
  __syncthreads();
  for (int o = 128; o > 0; o >>= 1) {
    if (t < o) cnt[t] += cnt[t + o];
    __syncthreads();
  }
  if (t == 0) flag[0] = (cnt[0] < 128) ? 1 : 0;  // 1 = f32 inputs
}

// ---------- T = Wa1@Wa2 ; vv = ba1@Wa2 + ba2 ----------
__global__ void prep_T(const void* __restrict__ Wa1, const void* __restrict__ ba1,
                       const void* __restrict__ Wa2, const void* __restrict__ ba2,
                       const int* __restrict__ flg, float* __restrict__ T, float* __restrict__ vv) {
  int isf = *flg;
  __shared__ float sW1[1024], sW2[1024];
  int t = threadIdx.x;
  sW1[t] = ldin(Wa1, t, isf);
  sW2[t] = ldin(Wa2, t, isf);
  __syncthreads();
  {
    int c = t >> 5, c2 = t & 31;
    float acc = 0.f;
    for (int k = 0; k < 32; k++) acc += sW1[c * 32 + k] * sW2[k * 32 + c2];
    T[c * 32 + c2] = acc;
  }
  if (t < 32) {
    float acc = ldin(ba2, t, isf);
    for (int k = 0; k < 32; k++) acc += ldin(ba1, k, isf) * sW2[k * 32 + t];
    vv[t] = acc;
  }
}

// ---------- M = T@Wa3 packed to MFMA B-frag (bf16); r2 = vv@Wa3 + ba3 ----------
__global__ void compute_Rp(const void* __restrict__ Wa3, const void* __restrict__ ba3,
                           const float* __restrict__ T, const float* __restrict__ vv,
                           const int* __restrict__ flg,
                           float* __restrict__ r2, unsigned short* __restrict__ Rp) {
  int isf = *flg;
  __shared__ float sT[1024], sv[32];
  int t = threadIdx.x;
  for (int i = t; i < 1024; i += 256) sT[i] = T[i];
  if (t < 32) sv[t] = vv[t];
  __syncthreads();
  int j = blockIdx.x * 256 + t;
  float w3[32];
  for (int c = 0; c < 32; c++) w3[c] = ldin(Wa3, c * NN + j, isf);
  float rr = ldin(ba3, j, isf);
  for (int c = 0; c < 32; c++) rr += sv[c] * w3[c];
  r2[j] = rr;
  float Rcol[32];
  for (int c = 0; c < 32; c++) {
    float acc = 0.f;
    for (int cp = 0; cp < 32; cp++) acc += sT[c * 32 + cp] * w3[cp];
    Rcol[c] = acc;
  }
  int jt = j >> 4, n = j & 15;
  for (int q = 0; q < 4; q++)
    for (int jj = 0; jj < 8; jj++)
      Rp[(size_t)(jt * 64 + q * 16 + n) * 8 + jj] = f2bf(Rcol[q * 8 + jj]);
}

// ---------- pack Wa0 [8192,32] into MFMA B-frag layout (bf16) ----------
__global__ void pack_Bp(const void* __restrict__ Wa0, const int* __restrict__ flg,
                        unsigned short* __restrict__ Bp) {
  int isf = *flg;
  int tid = blockIdx.x * 256 + threadIdx.x;  // 0..32767
  int kb = tid >> 7;
  int h = (tid >> 6) & 1;
  int L = tid & 63;
  int q = L >> 4, n = L & 15;
  int base_k = kb * 32 + q * 8;
  if (isf) {
    const float* W = (const float*)Wa0;
    for (int j = 0; j < 8; j++)
      Bp[(size_t)((kb * 2 + h) * 64 + L) * 8 + j] = f2bf(W[(base_k + j) * HD + h * 16 + n]);
  } else {
    const unsigned short* W = (const unsigned short*)Wa0;
    for (int j = 0; j < 8; j++)
      Bp[(size_t)((kb * 2 + h) * 64 + L) * 8 + j] = W[(base_k + j) * HD + h * 16 + n];
  }
}

// ---------- CSR build: degree histogram (int atomics, one-time) ----------
__global__ void deg_k(const int* __restrict__ dst, int* __restrict__ deg) {
  int e = blockIdx.x * 256 + threadIdx.x;
  atomicAdd(&deg[dst[e]], 1);
}

// ---------- exclusive scan of degrees -> row_ptr; dinv = rsqrt(deg+1) ----------
__global__ void csr_scan(const int* __restrict__ deg, int* __restrict__ rowp,
                         float* __restrict__ dinvf) {
  __shared__ int ps[1024];
  int t = threadIdx.x;
  int base = t * 8;
  int loc[8];
  int s = 0;
  for (int j = 0; j < 8; j++) {
    int d = deg[base + j];
    loc[j] = s;
    s += d;
    dinvf[base + j] = rsqrtf((float)d + 1.0f);  // +1 self-loop
  }
  ps[t] = s;
  __syncthreads();
  for (int off = 1; off < 1024; off <<= 1) {
    int v = (t >= off) ? ps[t - off] : 0;
    __syncthreads();
    if (t >= off) ps[t] += v;
    __syncthreads();
  }
  int ex = (t > 0) ? ps[t - 1] : 0;
  for (int j = 0; j < 8; j++) rowp[base + j] = ex + loc[j];
  if (t == 1023) rowp[NN] = ex + s;
}

// ---------- CSR fill: col[rowp[d] + pos] = src ----------
__global__ void csr_fill(const int* __restrict__ src, const int* __restrict__ dst,
                         const int* __restrict__ rowp, int* __restrict__ cnt,
                         int* __restrict__ col) {
  int e = blockIdx.x * 256 + threadIdx.x;
  int d = dst[e];
  int pos = atomicAdd(&cnt[d], 1);
  col[rowp[d] + pos] = src[e];
}

// ---------- h0 = dinv[row] * (x @ W0)  (prescaled for gather) ----------
__global__ void gemm_x_w0(const void* __restrict__ x, const void* __restrict__ W0,
                          const float* __restrict__ dinvf, const int* __restrict__ flg,
                          float* __restrict__ h0) {
  int isf = *flg;
  __shared__ float sW[FIN * HD];
  __shared__ float sx[8 * FIN];
  int t = threadIdx.x;
  for (int i = t; i < FIN * HD; i += 256) sW[i] = ldin(W0, i, isf);
  int row0 = blockIdx.x * 8;
  for (int i = t; i < 8 * FIN; i += 256) {
    int r = i >> 7, k = i & 127;
    sx[i] = ldin(x, (row0 + r) * FIN + k, isf);
  }
  __syncthreads();
  int r = t >> 5, c = t & 31;
  float acc = 0.f;
  for (int k = 0; k < FIN; k++) acc += sx[r * FIN + k] * sW[k * HD + c];
  h0[(row0 + r) * HD + c] = acc * dinvf[row0 + r];
}

// ---------- gather: agg[d] = dinv[d] * ( sum_{s in in(d)} hs[s] + hs[d] )  ----------
// hs rows are prescaled by dinv[s]. One wave per destination row; lanes = 32 feats x 2 edges.
__global__ void gather_agg(const int* __restrict__ rowp, const int* __restrict__ col,
                           const float* __restrict__ dinvf, const float* __restrict__ hs,
                           float* __restrict__ agg) {
  int w = (blockIdx.x << 2) + (threadIdx.x >> 6);  // destination row
  int L = threadIdx.x & 63;
  int c = L & 31, half = L >> 5;
  int s0 = rowp[w], s1 = rowp[w + 1];
  float acc = 0.f;
  int e = s0 + half;
  if (e < s1) {
    int s = col[e];
    for (e += 2; e < s1; e += 2) {
      int sn = col[e];                 // prefetch next index
      acc += hs[(size_t)s * HD + c];
      s = sn;
    }
    acc += hs[(size_t)s * HD + c];
  }
  acc += __shfl_xor(acc, 32);
  if (half == 0) {
    float tot = acc + hs[(size_t)w * HD + c];  // self-loop term
    agg[(size_t)w * HD + c] = dinvf[w] * tot;
  }
}

// ---------- BN column stats ----------
__global__ void bn_stats(const float* __restrict__ xin, float* __restrict__ sum, float* __restrict__ sq) {
  int t = threadIdx.x;
  int c = t & 31;
  int g = t >> 5;
  float s = 0.f, q = 0.f;
  for (int r = blockIdx.x * 8 + g; r < NN; r += 2048) {
    float v = xin[r * HD + c];
    s += v;
    q += v * v;
  }
  __shared__ float ss[256], qq[256];
  ss[t] = s; qq[t] = q;
  __syncthreads();
  if (t < 128) { ss[t] += ss[t + 128]; qq[t] += qq[t + 128]; }
  __syncthreads();
  if (t < 64) { ss[t] += ss[t + 64]; qq[t] += qq[t + 64]; }
  __syncthreads();
  if (t < 32) {
    atomicAdd(&sum[c], ss[t] + ss[t + 32]);
    atomicAdd(&sq[c], qq[t] + qq[t + 32]);
  }
}

__global__ void bn_coef(const float* __restrict__ sum, const float* __restrict__ sq,
                        const void* __restrict__ g, const void* __restrict__ be,
                        const int* __restrict__ flg, float* __restrict__ a, float* __restrict__ bb) {
  int isf = *flg;
  int c = threadIdx.x;
  if (c < 32) {
    float m = sum[c] * (1.0f / 8192.0f);
    float var = fmaxf(sq[c] * (1.0f / 8192.0f) - m * m, 0.0f);
    float rstd = rsqrtf(var + EPSBN);
    float ac = ldin(g, c, isf) * rstd;
    a[c] = ac;
    bb[c] = ldin(be, c, isf) - m * ac;
  }
}

// ---------- b1 = b @ Wa0 (MFMA, split-K x8 within one block, LDS reduce, plain store) ----
__global__ void gemm_b_wa0(const void* __restrict__ Bm, const unsigned short* __restrict__ Bp,
                           const int* __restrict__ flg, float* __restrict__ b1) {
  int isf = *flg;
  __shared__ float red[8][512];
  int t = threadIdx.x;          // 512 threads = 8 waves
  int kq = t >> 6;              // wave id = K-split
  int L = t & 63;
  int rt = blockIdx.x;          // 0..511 -> 16 rows each
  int q = L >> 4, n = L & 15;
  size_t aoff = (size_t)(rt * 16 + n) * NN + kq * 1024 + q * 8;
  f32x4 acc0 = {0.f, 0.f, 0.f, 0.f};
  f32x4 acc1 = {0.f, 0.f, 0.f, 0.f};
  int kb0 = kq * 32;
  if (isf) {
    const float* arow = (const float*)Bm + aoff;
    for (int i = 0; i < 32; i++) {
      f32x4 u0 = *(const f32x4*)(arow + i * 32);
      f32x4 u1 = *(const f32x4*)(arow + i * 32 + 4);
      union { unsigned short s[8]; short8 v; } au;
      au.s[0] = f2bf(u0[0]); au.s[1] = f2bf(u0[1]); au.s[2] = f2bf(u0[2]); au.s[3] = f2bf(u0[3]);
      au.s[4] = f2bf(u1[0]); au.s[5] = f2bf(u1[1]); au.s[6] = f2bf(u1[2]); au.s[7] = f2bf(u1[3]);
      const unsigned short* bpp = Bp + (size_t)((kb0 + i) * 2) * 512 + L * 8;
      acc0 = __builtin_amdgcn_mfma_f32_16x16x32_bf16(au.v, ld_bf8(bpp), acc0, 0, 0, 0);
      acc1 = __builtin_amdgcn_mfma_f32_16x16x32_bf16(au.v, ld_bf8(bpp + 512), acc1, 0, 0, 0);
    }
  } else {
    const unsigned short* arow = (const unsigned short*)Bm + aoff;
    for (int i = 0; i < 32; i++) {
      short8 a = ld_bf8(arow + i * 32);
      const unsigned short* bpp = Bp + (size_t)((kb0 + i) * 2) * 512 + L * 8;
      acc0 = __builtin_amdgcn_mfma_f32_16x16x32_bf16(a, ld_bf8(bpp), acc0, 0, 0, 0);
      acc1 = __builtin_amdgcn_mfma_f32_16x16x32_bf16(a, ld_bf8(bpp + 512), acc1, 0, 0, 0);
    }
  }
  for (int r = 0; r < 4; r++) {
    red[kq][(q * 4 + r) * 32 + n] = acc0[r];
    red[kq][(q * 4 + r) * 32 + n + 16] = acc1[r];
  }
  __syncthreads();
  float s = 0.f;
  for (int kw = 0; kw < 8; kw++) s += red[kw][t];
  b1[rt * 512 + t] = s;
}

// ---------- x0 = relu(a0*agg0+bb0); h1in(in-place over agg0) = x0 + b1 + ba0 ----------
__global__ void fuse0(float* __restrict__ aggA, const float* __restrict__ b1,
                      const void* __restrict__ ba0, const float* __restrict__ a,
                      const float* __restrict__ bb, const int* __restrict__ flg,
                      float* __restrict__ x0) {
  int isf = *flg;
  int i = blockIdx.x * 256 + threadIdx.x;
  int c = i & 31;
  float xv = fmaxf(a[c] * aggA[i] + bb[c], 0.0f);
  x0[i] = xv;
  aggA[i] = xv + b1[i] + ldin(ba0, c, isf);
}

// ---------- h1mat = dinv[row] * (h1in @ W1) (in-place safe: rows staged to LDS first) -----
__global__ void gemm_h_w1(float* __restrict__ hbuf, const void* __restrict__ W1,
                          const float* __restrict__ dinvf, const int* __restrict__ flg) {
  int isf = *flg;
  __shared__ float sW[1024], sh[256];
  int t = threadIdx.x;
  for (int i = t; i < 1024; i += 256) sW[i] = ldin(W1, i, isf);
  int row0 = blockIdx.x * 8;
  {
    int r = t >> 5, k = t & 31;
    sh[t] = hbuf[(row0 + r) * HD + k];
  }
  __syncthreads();
  int r = t >> 5, c = t & 31;
  float acc = 0.f;
  for (int k = 0; k < 32; k++) acc += sh[r * 32 + k] * sW[k * HD + c];
  hbuf[(row0 + r) * HD + c] = acc * dinvf[row0 + r];
}

// ---------- classifier (BN+ReLU of layer1 fused in): log_softmax([x0 x1] @ Wj + bj) -------
__global__ void classifier(const float* __restrict__ x0, const float* __restrict__ agg1,
                           const float* __restrict__ a1, const float* __restrict__ bb1,
                           const void* __restrict__ Wj, const void* __restrict__ bj,
                           const int* __restrict__ flg, void* __restrict__ outv) {
  int isf = *flg;
  __shared__ float sW[64 * NC];
  __shared__ float sb[NC];
  __shared__ float sa[HD], sbb[HD];
  __shared__ float sx0[64 * 33], sx1[64 * 33];
  int t = threadIdx.x;  // 64 threads, one row each
  for (int i = t; i < 64 * NC; i += 64) sW[i] = ldin(Wj, i, isf);
  if (t < NC) sb[t] = ldin(bj, t, isf);
  if (t < HD) { sa[t] = a1[t]; sbb[t] = bb1[t]; }
  int row0 = blockIdx.x * 64;
  for (int i = t; i < 64 * HD; i += 64) {
    int r = i >> 5, k = i & 31;
    sx0[r * 33 + k] = x0[(size_t)row0 * HD + i];
    sx1[r * 33 + k] = agg1[(size_t)row0 * HD + i];
  }
  __syncthreads();
  float lg[NC];
  for (int c = 0; c < NC; c++) lg[c] = sb[c];
  for (int k = 0; k < HD; k++) {
    float v = sx0[t * 33 + k];
    for (int c = 0; c < NC; c++) lg[c] += v * sW[k * NC + c];
  }
  for (int k = 0; k < HD; k++) {
    float v = fmaxf(sa[k] * sx1[t * 33 + k] + sbb[k], 0.0f);  // BN+ReLU on the fly
    for (int c = 0; c < NC; c++) lg[c] += v * sW[(HD + k) * NC + c];
  }
  float mx = lg[0];
  for (int c = 1; c < NC; c++) mx = fmaxf(mx, lg[c]);
  float se = 0.f;
  for (int c = 0; c < NC; c++) se += expf(lg[c] - mx);
  float lse = mx + logf(se);
  int row = row0 + t;
  if (isf) {
    float* o = (float*)outv;
    for (int c = 0; c < NC; c++) o[row * NC + c] = lg[c] - lse;
  } else {
    unsigned short* o = (unsigned short*)outv;
    for (int c = 0; c < NC; c++) o[row * NC + c] = f2bf(lg[c] - lse);
  }
}

// ---------- out1 = (b1+ba0) @ M + r2 (MFMA K=32). Reads ONLY d_ws buffers. ----------
__global__ void gemm_b4(const float* __restrict__ b1, const void* __restrict__ ba0,
                        const unsigned short* __restrict__ Rp, const float* __restrict__ r2,
                        const int* __restrict__ flg, void* __restrict__ outv) {
  int isf = *flg;
  int t = threadIdx.x;
  int w = (blockIdx.x << 2) + (t >> 6);
  int L = t & 63;
  int rt = w >> 3, jc = w & 7;
  int q = L >> 4, n = L & 15;
  const float* ap = b1 + (size_t)(rt * 16 + n) * HD + q * 8;
  union { unsigned short s[8]; short8 v; } au;
  for (int j = 0; j < 8; j++) au.s[j] = f2bf(ap[j] + ldin(ba0, q * 8 + j, isf));
  short8 afrag = au.v;
  int orow = rt * 16 + q * 4;
  float* of = (float*)outv + NN * NC;
  unsigned short* ob = (unsigned short*)outv + NN * NC;
  for (int jt = jc * 64; jt < (jc + 1) * 64; jt++) {
    short8 bfrag = ld_bf8(Rp + (size_t)(jt * 64 + L) * 8);
    f32x4 acc = {0.f, 0.f, 0.f, 0.f};
    acc = __builtin_amdgcn_mfma_f32_16x16x32_bf16(afrag, bfrag, acc, 0, 0, 0);
    int col = jt * 16 + n;
    float radd = r2[col];
    size_t base = (size_t)orow * NN + col;
    if (isf) {
      of[base] = acc[0] + radd;
      of[base + NN] = acc[1] + radd;
      of[base + 2 * NN] = acc[2] + radd;
      of[base + 3 * NN] = acc[3] + radd;
    } else {
      ob[base] = f2bf(acc[0] + radd);
      ob[base + NN] = f2bf(acc[1] + radd);
      ob[base + 2 * NN] = f2bf(acc[2] + radd);
      ob[base + 3 * NN] = f2bf(acc[3] + radd);
    }
  }
}

extern "C" void kernel_launch(void* const* d_in, const int* in_sizes, int n_in,
                              void* d_out, int out_size, void* d_ws, size_t ws_size,
                              hipStream_t stream) {
  const void* B   = d_in[0];
  const void* X   = d_in[1];
  const int* EI   = (const int*)d_in[2];
  const void* W0  = d_in[3];
  const void* W1  = d_in[5];
  const void* g0  = d_in[7];
  const void* be0 = d_in[8];
  const void* g1  = d_in[9];
  const void* be1 = d_in[10];
  const void* Wa0 = d_in[11];
  const void* ba0 = d_in[12];
  const void* Wa1 = d_in[13];
  const void* ba1 = d_in[14];
  const void* Wa2 = d_in[15];
  const void* ba2 = d_in[16];
  const void* Wa3 = d_in[17];
  const void* ba3 = d_in[18];
  const void* Wj  = d_in[19];
  const void* bj  = d_in[20];
  (void)in_sizes; (void)n_in; (void)ws_size;

  const int* esrc = EI;
  const int* edst = EI + NE;

  // ---- d_ws layout (only what gemm_b4 needs + tiny stats): ~1.6 MB total ----
  float* ws   = (float*)d_ws;
  int* flag   = (int*)ws;             // 16 floats
  float* stats = ws + 16;             // 256 (sums/sq/coefs)
  float* sum0 = stats, * sq0 = stats + 32, * sum1 = stats + 64, * sq1 = stats + 96;
  float* a0c = stats + 128, * bb0c = stats + 160, * a1c = stats + 192, * bb1c = stats + 224;
  float* b1   = stats + 256;          // NN*HD (fully written by gemm_b_wa0, no zero needed)
  float* r2   = b1 + NN * HD;         // NN
  float* T    = r2 + NN;              // 1024
  float* vv   = T + 1024;             // 32
  unsigned short* Rp = (unsigned short*)(vv + 32);  // 512*64*8 bf16 = 512 KB

  // ---- big scratch inside d_out's out1 region (>=134 MB, overwritten by gemm_b4 last) ----
  size_t outBytesMin = (size_t)out_size * 2;
  size_t scratchBytes = (size_t)(NN + 3 * NN * HD) * 4        // degf + aggA + aggB + x0h
                      + (size_t)(256 * 2 * 64 * 8) * 2        // Bp
                      + (size_t)(3 * NN + 1 + NE) * 4;        // deg_i + cnt + rowp + col
  char* sc = (char*)d_out + ((outBytesMin - scratchBytes) & ~(size_t)255);
  float* degf = (float*)sc;           // NN   dinv values
  float* aggA = degf + NN;            // NN*HD (agg0 -> h1in -> h1mat)
  float* aggB = aggA + NN * HD;       // NN*HD (agg1, BN'd on the fly in classifier)
  float* x0h  = aggB + NN * HD;       // NN*HD (hs0 -> x0)
  unsigned short* Bp = (unsigned short*)(x0h + NN * HD);  // 512 KB
  int* deg_i  = (int*)(Bp + 256 * 2 * 64 * 8);  // NN (zeroed)
  int* cnt    = deg_i + NN;                     // NN (zeroed)
  int* rowp   = cnt + NN;                       // NN+1
  int* col    = rowp + NN + 1;                  // NE

  hipMemsetAsync(ws, 0, (size_t)(16 + 256) * sizeof(float), stream);
  hipMemsetAsync(deg_i, 0, (size_t)2 * NN * sizeof(int), stream);

  detect_k<<<1, 256, 0, stream>>>(B, flag);
  prep_T<<<1, 1024, 0, stream>>>(Wa1, ba1, Wa2, ba2, flag, T, vv);
  compute_Rp<<<32, 256, 0, stream>>>(Wa3, ba3, T, vv, flag, r2, Rp);
  pack_Bp<<<128, 256, 0, stream>>>(Wa0, flag, Bp);
  deg_k<<<NE / 256, 256, 0, stream>>>(edst, deg_i);
  csr_scan<<<1, 1024, 0, stream>>>(deg_i, rowp, degf);
  csr_fill<<<NE / 256, 256, 0, stream>>>(esrc, edst, rowp, cnt, col);
  gemm_x_w0<<<NN / 8, 256, 0, stream>>>(X, W0, degf, flag, x0h);   // hs0 (prescaled)
  gemm_b_wa0<<<512, 512, 0, stream>>>(B, Bp, flag, b1);
  gather_agg<<<NN / 4, 256, 0, stream>>>(rowp, col, degf, x0h, aggA);       // agg0
  bn_stats<<<256, 256, 0, stream>>>(aggA, sum0, sq0);
  bn_coef<<<1, 64, 0, stream>>>(sum0, sq0, g0, be0, flag, a0c, bb0c);
  fuse0<<<NN * HD / 256, 256, 0, stream>>>(aggA, b1, ba0, a0c, bb0c, flag, x0h);  // aggA<-h1in, x0h<-x0
  gemm_h_w1<<<NN / 8, 256, 0, stream>>>(aggA, W1, degf, flag);     // aggA<-hs1 (in place, prescaled)
  gather_agg<<<NN / 4, 256, 0, stream>>>(rowp, col, degf, aggA, aggB);      // agg1
  bn_stats<<<256, 256, 0, stream>>>(aggB, sum1, sq1);
  bn_coef<<<1, 64, 0, stream>>>(sum1, sq1, g1, be1, flag, a1c, bb1c);
  classifier<<<NN / 64, 64, 0, stream>>>(x0h, aggB, a1c, bb1c, Wj, bj, flag, d_out);
  gemm_b4<<<1024, 256, 0, stream>>>(b1, ba0, Rp, r2, flag, d_out);  // overwrites all scratch in out1
}

// Round 2
// 748.041 us; speedup vs baseline: 1.0326x; 1.0326x over previous
//
#include <hip/hip_runtime.h>
#include <math.h>

#define NN 8192
#define FIN 128
#define HD 32
#define NC 10
#define NE 262144
#define EPSBN 1e-5f

typedef short short8 __attribute__((ext_vector_type(8)));
typedef float f32x4 __attribute__((ext_vector_type(4)));
typedef unsigned short us4 __attribute__((ext_vector_type(4)));

__device__ __forceinline__ float bf2f(unsigned short b) {
  unsigned int u = ((unsigned int)b) << 16;
  float f;
  __builtin_memcpy(&f, &u, 4);
  return f;
}
__device__ __forceinline__ unsigned short f2bf(float f) {
  unsigned int u;
  __builtin_memcpy(&u, &f, 4);
  u = u + 0x7fffu + ((u >> 16) & 1u);
  return (unsigned short)(u >> 16);
}
__device__ __forceinline__ short8 ld_bf8(const unsigned short* p) {
  uint4 u = *(const uint4*)p;
  return __builtin_bit_cast(short8, u);
}
__device__ __forceinline__ float ldin(const void* p, int i, int isf) {
  if (isf) return ((const float*)p)[i];
  return bf2f(((const unsigned short*)p)[i]);
}

// ---------- dtype detect + zero stats + zero deg/cnt (replaces 2 memsets) ----------
__global__ void detect_k(const void* __restrict__ b, int* __restrict__ flag,
                         float* __restrict__ stats, int* __restrict__ dz) {
  const unsigned short* p = (const unsigned short*)b;
  int t = threadIdx.x;
  unsigned short s = p[2 * t];
  int e = (s >> 7) & 0xFF;
  int hit = (e >= 110 && e <= 135) ? 1 : 0;
  __shared__ int cnt[256];
  cnt[t] = hit;
  stats[t] = 0.0f;                                  // zero 256 stat floats
  for (int i = t; i < 2 * NN; i += 256) dz[i] = 0;  // zero deg_i + cnt
  __syncthreads();
  for (int o = 128; o > 0; o >>= 1) {
    if (t < o) cnt[t] += cnt[t + o];
    __syncthreads();
  }
  if (t == 0) flag[0] = (cnt[0] < 128) ? 1 : 0;  // 1 = f32 inputs
}

// ---------- T=Wa1@Wa2, vv=ba1@Wa2+ba2 (in-LDS, redundant/block); M=T@Wa3 -> Rp; r2 ----
__global__ void compute_Rp(const void* __restrict__ Wa1, const void* __restrict__ ba1,
                           const void* __restrict__ Wa2, const void* __restrict__ ba2,
                           const void* __restrict__ Wa3, const void* __restrict__ ba3,
                           const int* __restrict__ flg,
                           float* __restrict__ r2, unsigned short* __restrict__ Rp) {
  int isf = *flg;
  __shared__ float sW1[1024], sW2[1024], sT[1024], sv[32];
  int t = threadIdx.x;
  for (int i = t; i < 1024; i += 256) {
    sW1[i] = ldin(Wa1, i, isf);
    sW2[i] = ldin(Wa2, i, isf);
  }
  __syncthreads();
  for (int i = t; i < 1024; i += 256) {
    int c = i >> 5, c2 = i & 31;
    float acc = 0.f;
    for (int k = 0; k < 32; k++) acc += sW1[c * 32 + k] * sW2[k * 32 + c2];
    sT[i] = acc;
  }
  if (t < 32) {
    float acc = ldin(ba2, t, isf);
    for (int k = 0; k < 32; k++) acc += ldin(ba1, k, isf) * sW2[k * 32 + t];
    sv[t] = acc;
  }
  __syncthreads();
  int j = blockIdx.x * 256 + t;
  float w3[32];
  for (int c = 0; c < 32; c++) w3[c] = ldin(Wa3, c * NN + j, isf);
  float rr = ldin(ba3, j, isf);
  for (int c = 0; c < 32; c++) rr += sv[c] * w3[c];
  r2[j] = rr;
  float Rcol[32];
  for (int c = 0; c < 32; c++) {
    float acc = 0.f;
    for (int cp = 0; cp < 32; cp++) acc += sT[c * 32 + cp] * w3[cp];
    Rcol[c] = acc;
  }
  int jt = j >> 4, n = j & 15;
  for (int q = 0; q < 4; q++)
    for (int jj = 0; jj < 8; jj++)
      Rp[(size_t)(jt * 64 + q * 16 + n) * 8 + jj] = f2bf(Rcol[q * 8 + jj]);
}

// ---------- pack Wa0 [8192,32] into MFMA frag layout (bf16) ----------
__global__ void pack_Bp(const void* __restrict__ Wa0, const int* __restrict__ flg,
                        unsigned short* __restrict__ Bp) {
  int isf = *flg;
  int tid = blockIdx.x * 256 + threadIdx.x;  // 0..32767
  int kb = tid >> 7;
  int h = (tid >> 6) & 1;
  int L = tid & 63;
  int q = L >> 4, n = L & 15;
  int base_k = kb * 32 + q * 8;
  if (isf) {
    const float* W = (const float*)Wa0;
    for (int j = 0; j < 8; j++)
      Bp[(size_t)((kb * 2 + h) * 64 + L) * 8 + j] = f2bf(W[(base_k + j) * HD + h * 16 + n]);
  } else {
    const unsigned short* W = (const unsigned short*)Wa0;
    for (int j = 0; j < 8; j++)
      Bp[(size_t)((kb * 2 + h) * 64 + L) * 8 + j] = W[(base_k + j) * HD + h * 16 + n];
  }
}

// ---------- CSR build: degree histogram (int atomics, one-time) ----------
__global__ void deg_k(const int* __restrict__ dst, int* __restrict__ deg) {
  int e = blockIdx.x * 256 + threadIdx.x;
  atomicAdd(&deg[dst[e]], 1);
}

// ---------- exclusive scan of degrees -> row_ptr; dinv = rsqrt(deg+1) ----------
__global__ void csr_scan(const int* __restrict__ deg, int* __restrict__ rowp,
                         float* __restrict__ dinvf) {
  __shared__ int ps[1024];
  int t = threadIdx.x;
  int base = t * 8;
  int loc[8];
  int s = 0;
  for (int j = 0; j < 8; j++) {
    int d = deg[base + j];
    loc[j] = s;
    s += d;
    dinvf[base + j] = rsqrtf((float)d + 1.0f);  // +1 self-loop
  }
  ps[t] = s;
  __syncthreads();
  for (int off = 1; off < 1024; off <<= 1) {
    int v = (t >= off) ? ps[t - off] : 0;
    __syncthreads();
    if (t >= off) ps[t] += v;
    __syncthreads();
  }
  int ex = (t > 0) ? ps[t - 1] : 0;
  for (int j = 0; j < 8; j++) rowp[base + j] = ex + loc[j];
  if (t == 1023) rowp[NN] = ex + s;
}

// ---------- CSR fill: col[rowp[d] + pos] = src ----------
__global__ void csr_fill(const int* __restrict__ src, const int* __restrict__ dst,
                         const int* __restrict__ rowp, int* __restrict__ cnt,
                         int* __restrict__ col) {
  int e = blockIdx.x * 256 + threadIdx.x;
  int d = dst[e];
  int pos = atomicAdd(&cnt[d], 1);
  col[rowp[d] + pos] = src[e];
}

// ---------- h0 = dinv[row] * (x @ W0)  (prescaled for gather) ----------
__global__ void gemm_x_w0(const void* __restrict__ x, const void* __restrict__ W0,
                          const float* __restrict__ dinvf, const int* __restrict__ flg,
                          float* __restrict__ h0) {
  int isf = *flg;
  __shared__ float sW[FIN * HD];
  __shared__ float sx[8 * FIN];
  int t = threadIdx.x;
  for (int i = t; i < FIN * HD; i += 256) sW[i] = ldin(W0, i, isf);
  int row0 = blockIdx.x * 8;
  for (int i = t; i < 8 * FIN; i += 256) {
    int r = i >> 7, k = i & 127;
    sx[i] = ldin(x, (row0 + r) * FIN + k, isf);
  }
  __syncthreads();
  int r = t >> 5, c = t & 31;
  float acc = 0.f;
  for (int k = 0; k < FIN; k++) acc += sx[r * FIN + k] * sW[k * HD + c];
  h0[(row0 + r) * HD + c] = acc * dinvf[row0 + r];
}

// ---------- gather: agg[d] = dinv[d] * ( sum_{s in in(d)} hs[s] + hs[d] ) ----------
__global__ void gather_agg(const int* __restrict__ rowp, const int* __restrict__ col,
                           const float* __restrict__ dinvf, const float* __restrict__ hs,
                           float* __restrict__ agg) {
  int w = (blockIdx.x << 2) + (threadIdx.x >> 6);  // destination row
  int L = threadIdx.x & 63;
  int c = L & 31, half = L >> 5;
  int s0 = rowp[w], s1 = rowp[w + 1];
  float acc = 0.f;
  int e = s0 + half;
  if (e < s1) {
    int s = col[e];
    for (e += 2; e < s1; e += 2) {
      int sn = col[e];  // prefetch next index
      acc += hs[(size_t)s * HD + c];
      s = sn;
    }
    acc += hs[(size_t)s * HD + c];
  }
  acc += __shfl_xor(acc, 32);
  if (half == 0) {
    float tot = acc + hs[(size_t)w * HD + c];  // self-loop term
    agg[(size_t)w * HD + c] = dinvf[w] * tot;
  }
}

// ---------- BN column stats ----------
__global__ void bn_stats(const float* __restrict__ xin, float* __restrict__ sum, float* __restrict__ sq) {
  int t = threadIdx.x;
  int c = t & 31;
  int g = t >> 5;
  float s = 0.f, q = 0.f;
  for (int r = blockIdx.x * 8 + g; r < NN; r += 2048) {
    float v = xin[r * HD + c];
    s += v;
    q += v * v;
  }
  __shared__ float ss[256], qq[256];
  ss[t] = s; qq[t] = q;
  __syncthreads();
  if (t < 128) { ss[t] += ss[t + 128]; qq[t] += qq[t + 128]; }
  __syncthreads();
  if (t < 64) { ss[t] += ss[t + 64]; qq[t] += qq[t + 64]; }
  __syncthreads();
  if (t < 32) {
    atomicAdd(&sum[c], ss[t] + ss[t + 32]);
    atomicAdd(&sq[c], qq[t] + qq[t + 32]);
  }
}

// ---------- fused: bn_coef0 + x0=relu(BN(agg0)) + h1in=x0+b1+ba0 + h1mat=dinv*(h1in@W1) --
// In-place: hs1 written over aggA (each block reads/writes only its own 16 rows).
__global__ void fuse0_w1(float* __restrict__ aggA, const float* __restrict__ b1,
                         const void* __restrict__ ba0, const void* __restrict__ W1,
                         const float* __restrict__ sum0, const float* __restrict__ sq0,
                         const void* __restrict__ g0, const void* __restrict__ be0,
                         const float* __restrict__ dinvf, const int* __restrict__ flg,
                         float* __restrict__ x0) {
  int isf = *flg;
  __shared__ float sW[1024], sh[16 * 33];
  int t = threadIdx.x;  // 512 threads
  for (int i = t; i < 1024; i += 512) sW[i] = ldin(W1, i, isf);
  int r = t >> 5, c = t & 31;
  int row = blockIdx.x * 16 + r;
  float m = sum0[c] * (1.0f / 8192.0f);
  float var = fmaxf(sq0[c] * (1.0f / 8192.0f) - m * m, 0.0f);
  float ac = ldin(g0, c, isf) * rsqrtf(var + EPSBN);
  float bc = ldin(be0, c, isf) - m * ac;
  float v = aggA[row * HD + c];
  float xv = fmaxf(ac * v + bc, 0.0f);
  x0[row * HD + c] = xv;
  sh[r * 33 + c] = xv + b1[row * HD + c] + ldin(ba0, c, isf);
  __syncthreads();
  float acc = 0.f;
  for (int k = 0; k < 32; k++) acc += sh[r * 33 + k] * sW[k * HD + c];
  aggA[row * HD + c] = acc * dinvf[row];
}

// ---------- b1 = b @ Wa0 (MFMA, split-K x8 within one block, LDS reduce, plain store) ----
__global__ void gemm_b_wa0(const void* __restrict__ Bm, const unsigned short* __restrict__ Bp,
                           const int* __restrict__ flg, float* __restrict__ b1) {
  int isf = *flg;
  __shared__ float red[8][512];
  int t = threadIdx.x;  // 512 threads = 8 waves
  int kq = t >> 6;      // wave id = K-split
  int L = t & 63;
  int rt = blockIdx.x;  // 0..511 -> 16 rows each
  int q = L >> 4, n = L & 15;
  size_t aoff = (size_t)(rt * 16 + n) * NN + kq * 1024 + q * 8;
  f32x4 acc0 = {0.f, 0.f, 0.f, 0.f};
  f32x4 acc1 = {0.f, 0.f, 0.f, 0.f};
  int kb0 = kq * 32;
  if (isf) {
    const float* arow = (const float*)Bm + aoff;
    for (int i = 0; i < 32; i++) {
      f32x4 u0 = *(const f32x4*)(arow + i * 32);
      f32x4 u1 = *(const f32x4*)(arow + i * 32 + 4);
      union { unsigned short s[8]; short8 v; } au;
      au.s[0] = f2bf(u0[0]); au.s[1] = f2bf(u0[1]); au.s[2] = f2bf(u0[2]); au.s[3] = f2bf(u0[3]);
      au.s[4] = f2bf(u1[0]); au.s[5] = f2bf(u1[1]); au.s[6] = f2bf(u1[2]); au.s[7] = f2bf(u1[3]);
      const unsigned short* bpp = Bp + (size_t)((kb0 + i) * 2) * 512 + L * 8;
      acc0 = __builtin_amdgcn_mfma_f32_16x16x32_bf16(au.v, ld_bf8(bpp), acc0, 0, 0, 0);
      acc1 = __builtin_amdgcn_mfma_f32_16x16x32_bf16(au.v, ld_bf8(bpp + 512), acc1, 0, 0, 0);
    }
  } else {
    const unsigned short* arow = (const unsigned short*)Bm + aoff;
    for (int i = 0; i < 32; i++) {
      short8 a = ld_bf8(arow + i * 32);
      const unsigned short* bpp = Bp + (size_t)((kb0 + i) * 2) * 512 + L * 8;
      acc0 = __builtin_amdgcn_mfma_f32_16x16x32_bf16(a, ld_bf8(bpp), acc0, 0, 0, 0);
      acc1 = __builtin_amdgcn_mfma_f32_16x16x32_bf16(a, ld_bf8(bpp + 512), acc1, 0, 0, 0);
    }
  }
  for (int r = 0; r < 4; r++) {
    red[kq][(q * 4 + r) * 32 + n] = acc0[r];
    red[kq][(q * 4 + r) * 32 + n + 16] = acc1[r];
  }
  __syncthreads();
  float s = 0.f;
  for (int kw = 0; kw < 8; kw++) s += red[kw][t];
  b1[rt * 512 + t] = s;
}

// ---------- classifier (bn_coef1 inlined): log_softmax([x0 x1] @ Wj + bj) ----------
__global__ void classifier(const float* __restrict__ x0, const float* __restrict__ agg1,
                           const float* __restrict__ sum1, const float* __restrict__ sq1,
                           const void* __restrict__ g1, const void* __restrict__ be1,
                           const void* __restrict__ Wj, const void* __restrict__ bj,
                           const int* __restrict__ flg, void* __restrict__ outv) {
  int isf = *flg;
  __shared__ float sW[64 * NC];
  __shared__ float sb[NC];
  __shared__ float sa[HD], sbb[HD];
  __shared__ float sx0[64 * 33], sx1[64 * 33];
  int t = threadIdx.x;  // 64 threads, one row each
  for (int i = t; i < 64 * NC; i += 64) sW[i] = ldin(Wj, i, isf);
  if (t < NC) sb[t] = ldin(bj, t, isf);
  if (t < HD) {
    float m = sum1[t] * (1.0f / 8192.0f);
    float var = fmaxf(sq1[t] * (1.0f / 8192.0f) - m * m, 0.0f);
    float ac = ldin(g1, t, isf) * rsqrtf(var + EPSBN);
    sa[t] = ac;
    sbb[t] = ldin(be1, t, isf) - m * ac;
  }
  int row0 = blockIdx.x * 64;
  for (int i = t; i < 64 * HD; i += 64) {
    int r = i >> 5, k = i & 31;
    sx0[r * 33 + k] = x0[(size_t)row0 * HD + i];
    sx1[r * 33 + k] = agg1[(size_t)row0 * HD + i];
  }
  __syncthreads();
  float lg[NC];
  for (int c = 0; c < NC; c++) lg[c] = sb[c];
  for (int k = 0; k < HD; k++) {
    float v = sx0[t * 33 + k];
    for (int c = 0; c < NC; c++) lg[c] += v * sW[k * NC + c];
  }
  for (int k = 0; k < HD; k++) {
    float v = fmaxf(sa[k] * sx1[t * 33 + k] + sbb[k], 0.0f);  // BN+ReLU on the fly
    for (int c = 0; c < NC; c++) lg[c] += v * sW[(HD + k) * NC + c];
  }
  float mx = lg[0];
  for (int c = 1; c < NC; c++) mx = fmaxf(mx, lg[c]);
  float se = 0.f;
  for (int c = 0; c < NC; c++) se += expf(lg[c] - mx);
  float lse = mx + logf(se);
  int row = row0 + t;
  if (isf) {
    float* o = (float*)outv;
    for (int c = 0; c < NC; c++) o[row * NC + c] = lg[c] - lse;
  } else {
    unsigned short* o = (unsigned short*)outv;
    for (int c = 0; c < NC; c++) o[row * NC + c] = f2bf(lg[c] - lse);
  }
}

// ---------- out1 = (b1+ba0) @ M + r2. Operand-swapped MFMA -> per-lane 4 consecutive
// columns -> one dwordx4 store per tile. Reads ONLY d_ws buffers. ----------
__global__ void gemm_b4(const float* __restrict__ b1, const void* __restrict__ ba0,
                        const unsigned short* __restrict__ Rp, const float* __restrict__ r2,
                        const int* __restrict__ flg, void* __restrict__ outv) {
  int isf = *flg;
  int t = threadIdx.x;
  int w = (blockIdx.x << 2) + (t >> 6);
  int L = t & 63;
  int rt = w >> 3, jc = w & 7;
  int q = L >> 4, n = L & 15;
  // B-operand frag: B[k][n] = (b1+ba0)[row = rt*16+n][k = q*8+j]
  const float* ap = b1 + (size_t)(rt * 16 + n) * HD + q * 8;
  union { unsigned short s[8]; short8 v; } au;
  for (int j = 0; j < 8; j++) au.s[j] = f2bf(ap[j] + ldin(ba0, q * 8 + j, isf));
  short8 bfrag = au.v;
  int orow = rt * 16 + n;  // this lane's output row
  float* of = (float*)outv + NN * NC;
  unsigned short* ob = (unsigned short*)outv + NN * NC;
  for (int jt = jc * 64; jt < (jc + 1) * 64; jt++) {
    // A-operand frag: A[m][k] = M[k = q*8+j][col = jt*16 + n]  (same packed bytes)
    short8 afrag = ld_bf8(Rp + (size_t)(jt * 64 + L) * 8);
    f32x4 acc = {0.f, 0.f, 0.f, 0.f};
    acc = __builtin_amdgcn_mfma_f32_16x16x32_bf16(afrag, bfrag, acc, 0, 0, 0);
    int col = jt * 16 + q * 4;  // 4 consecutive columns per lane
    f32x4 radd = *(const f32x4*)(r2 + col);
    f32x4 res = acc + radd;
    size_t base = (size_t)orow * NN + col;
    if (isf) {
      *(f32x4*)(of + base) = res;
    } else {
      us4 pk;
      pk[0] = f2bf(res[0]); pk[1] = f2bf(res[1]); pk[2] = f2bf(res[2]); pk[3] = f2bf(res[3]);
      *(us4*)(ob + base) = pk;
    }
  }
}

extern "C" void kernel_launch(void* const* d_in, const int* in_sizes, int n_in,
                              void* d_out, int out_size, void* d_ws, size_t ws_size,
                              hipStream_t stream) {
  const void* B   = d_in[0];
  const void* X   = d_in[1];
  const int* EI   = (const int*)d_in[2];
  const void* W0  = d_in[3];
  const void* W1  = d_in[5];
  const void* g0  = d_in[7];
  const void* be0 = d_in[8];
  const void* g1  = d_in[9];
  const void* be1 = d_in[10];
  const void* Wa0 = d_in[11];
  const void* ba0 = d_in[12];
  const void* Wa1 = d_in[13];
  const void* ba1 = d_in[14];
  const void* Wa2 = d_in[15];
  const void* ba2 = d_in[16];
  const void* Wa3 = d_in[17];
  const void* ba3 = d_in[18];
  const void* Wj  = d_in[19];
  const void* bj  = d_in[20];
  (void)in_sizes; (void)n_in; (void)ws_size;

  const int* esrc = EI;
  const int* edst = EI + NE;

  // ---- d_ws layout (only what gemm_b4 needs + tiny stats): ~1.6 MB total ----
  float* ws   = (float*)d_ws;
  int* flag   = (int*)ws;             // 16 floats
  float* stats = ws + 16;             // 256 (sum0,sq0,sum1,sq1 + pad)
  float* sum0 = stats, * sq0 = stats + 32, * sum1 = stats + 64, * sq1 = stats + 96;
  float* b1   = stats + 256;          // NN*HD (fully written by gemm_b_wa0)
  float* r2   = b1 + NN * HD;         // NN
  unsigned short* Rp = (unsigned short*)(r2 + NN);  // 512*64*8 bf16 = 512 KB

  // ---- big scratch inside d_out's out1 region (>=134 MB, overwritten by gemm_b4 last) ----
  size_t outBytesMin = (size_t)out_size * 2;
  size_t scratchBytes = (size_t)(NN + 3 * NN * HD) * 4        // degf + aggA + aggB + x0h
                      + (size_t)(256 * 2 * 64 * 8) * 2        // Bp
                      + (size_t)(3 * NN + 1 + NE) * 4;        // deg_i + cnt + rowp + col
  char* sc = (char*)d_out + ((outBytesMin - scratchBytes) & ~(size_t)255);
  float* degf = (float*)sc;           // NN   dinv values
  float* aggA = degf + NN;            // NN*HD (agg0 -> hs1 in place)
  float* aggB = aggA + NN * HD;       // NN*HD (agg1, BN'd on the fly in classifier)
  float* x0h  = aggB + NN * HD;       // NN*HD (hs0 -> x0)
  unsigned short* Bp = (unsigned short*)(x0h + NN * HD);  // 512 KB
  int* deg_i  = (int*)(Bp + 256 * 2 * 64 * 8);  // NN (zeroed in detect_k)
  int* cnt    = deg_i + NN;                     // NN (zeroed in detect_k)
  int* rowp   = cnt + NN;                       // NN+1
  int* col    = rowp + NN + 1;                  // NE

  detect_k<<<1, 256, 0, stream>>>(B, flag, stats, deg_i);
  compute_Rp<<<32, 256, 0, stream>>>(Wa1, ba1, Wa2, ba2, Wa3, ba3, flag, r2, Rp);
  pack_Bp<<<128, 256, 0, stream>>>(Wa0, flag, Bp);
  deg_k<<<NE / 256, 256, 0, stream>>>(edst, deg_i);
  csr_scan<<<1, 1024, 0, stream>>>(deg_i, rowp, degf);
  csr_fill<<<NE / 256, 256, 0, stream>>>(esrc, edst, rowp, cnt, col);
  gemm_x_w0<<<NN / 8, 256, 0, stream>>>(X, W0, degf, flag, x0h);   // hs0 (prescaled)
  gemm_b_wa0<<<512, 512, 0, stream>>>(B, Bp, flag, b1);
  gather_agg<<<NN / 4, 256, 0, stream>>>(rowp, col, degf, x0h, aggA);       // agg0
  bn_stats<<<256, 256, 0, stream>>>(aggA, sum0, sq0);
  fuse0_w1<<<NN / 16, 512, 0, stream>>>(aggA, b1, ba0, W1, sum0, sq0, g0, be0,
                                        degf, flag, x0h);          // aggA<-hs1, x0h<-x0
  gather_agg<<<NN / 4, 256, 0, stream>>>(rowp, col, degf, aggA, aggB);      // agg1
  bn_stats<<<256, 256, 0, stream>>>(aggB, sum1, sq1);
  classifier<<<NN / 64, 64, 0, stream>>>(x0h, aggB, sum1, sq1, g1, be1, Wj, bj, flag, d_out);
  gemm_b4<<<1024, 256, 0, stream>>>(b1, ba0, Rp, r2, flag, d_out);  // overwrites all scratch
}

// Round 3
// 746.016 us; speedup vs baseline: 1.0354x; 1.0027x over previous
//
#include <hip/hip_runtime.h>
#include <math.h>

#define NN 8192
#define FIN 128
#define HD 32
#define NC 10
#define NE 262144
#define EPSBN 1e-5f

typedef short short8 __attribute__((ext_vector_type(8)));
typedef float f32x4 __attribute__((ext_vector_type(4)));
typedef unsigned short us4 __attribute__((ext_vector_type(4)));

__device__ __forceinline__ float bf2f(unsigned short b) {
  unsigned int u = ((unsigned int)b) << 16;
  float f;
  __builtin_memcpy(&f, &u, 4);
  return f;
}
__device__ __forceinline__ unsigned short f2bf(float f) {
  unsigned int u;
  __builtin_memcpy(&u, &f, 4);
  u = u + 0x7fffu + ((u >> 16) & 1u);
  return (unsigned short)(u >> 16);
}
__device__ __forceinline__ short8 ld_bf8(const unsigned short* p) {
  uint4 u = *(const uint4*)p;
  return __builtin_bit_cast(short8, u);
}
__device__ __forceinline__ float ldin(const void* p, int i, int isf) {
  if (isf) return ((const float*)p)[i];
  return bf2f(((const unsigned short*)p)[i]);
}

// Per-wave dtype detect: sample 64 even-indexed shorts of b. bf16 values of N(0,1)
// have exponent in [110,135] essentially always; f32 low-mantissa halves are random
// (P(hit) ~ 0.1). Threshold 33/64: error probability is astronomically small.
__device__ __forceinline__ int wave_detect(const void* b) {
  const unsigned short* p = (const unsigned short*)b;
  int lane = threadIdx.x & 63;
  unsigned short s = p[2 * lane];
  int e = (s >> 7) & 0xFF;
  unsigned long long m = __ballot(e >= 110 && e <= 135);
  return (__popcll(m) < 33) ? 1 : 0;  // 1 = f32 inputs
}

// ---------- role-split prep: [0,32) compute_Rp | [32,160) pack_Bp | [160,1184) deg hist --
__global__ void prep_all(const void* __restrict__ B,
                         const void* __restrict__ Wa1, const void* __restrict__ ba1,
                         const void* __restrict__ Wa2, const void* __restrict__ ba2,
                         const void* __restrict__ Wa3, const void* __restrict__ ba3,
                         const void* __restrict__ Wa0, const int* __restrict__ edst,
                         int* __restrict__ deg, float* __restrict__ r2,
                         unsigned short* __restrict__ Rp, unsigned short* __restrict__ Bp) {
  int bid = blockIdx.x;
  int t = threadIdx.x;
  if (bid >= 160) {  // ---- degree histogram (deg pre-zeroed by memset) ----
    int e = (bid - 160) * 256 + t;
    atomicAdd(&deg[edst[e]], 1);
    return;
  }
  int isf = wave_detect(B);
  if (bid >= 32) {  // ---- pack Wa0 [8192,32] into MFMA frag layout (bf16) ----
    int tid = (bid - 32) * 256 + t;  // 0..32767
    int kb = tid >> 7;
    int h = (tid >> 6) & 1;
    int L = tid & 63;
    int q = L >> 4, n = L & 15;
    int base_k = kb * 32 + q * 8;
    if (isf) {
      const float* W = (const float*)Wa0;
      for (int j = 0; j < 8; j++)
        Bp[(size_t)((kb * 2 + h) * 64 + L) * 8 + j] = f2bf(W[(base_k + j) * HD + h * 16 + n]);
    } else {
      const unsigned short* W = (const unsigned short*)Wa0;
      for (int j = 0; j < 8; j++)
        Bp[(size_t)((kb * 2 + h) * 64 + L) * 8 + j] = W[(base_k + j) * HD + h * 16 + n];
    }
    return;
  }
  // ---- compute_Rp: T=Wa1@Wa2, vv=ba1@Wa2+ba2 (in LDS); M=T@Wa3 -> Rp; r2=vv@Wa3+ba3 ----
  __shared__ float sW1[1024], sW2[1024], sT[1024], sv[32];
  for (int i = t; i < 1024; i += 256) {
    sW1[i] = ldin(Wa1, i, isf);
    sW2[i] = ldin(Wa2, i, isf);
  }
  __syncthreads();
  for (int i = t; i < 1024; i += 256) {
    int c = i >> 5, c2 = i & 31;
    float acc = 0.f;
    for (int k = 0; k < 32; k++) acc += sW1[c * 32 + k] * sW2[k * 32 + c2];
    sT[i] = acc;
  }
  if (t < 32) {
    float acc = ldin(ba2, t, isf);
    for (int k = 0; k < 32; k++) acc += ldin(ba1, k, isf) * sW2[k * 32 + t];
    sv[t] = acc;
  }
  __syncthreads();
  int j = bid * 256 + t;
  float w3[32];
  for (int c = 0; c < 32; c++) w3[c] = ldin(Wa3, c * NN + j, isf);
  float rr = ldin(ba3, j, isf);
  for (int c = 0; c < 32; c++) rr += sv[c] * w3[c];
  r2[j] = rr;
  float Rcol[32];
  for (int c = 0; c < 32; c++) {
    float acc = 0.f;
    for (int cp = 0; cp < 32; cp++) acc += sT[c * 32 + cp] * w3[cp];
    Rcol[c] = acc;
  }
  int jt = j >> 4, n = j & 15;
  for (int q = 0; q < 4; q++)
    for (int jj = 0; jj < 8; jj++)
      Rp[(size_t)(jt * 64 + q * 16 + n) * 8 + jj] = f2bf(Rcol[q * 8 + jj]);
}

// ---------- exclusive scan of degrees -> row_ptr; dinv = rsqrt(deg+1); zero stats ------
__global__ void csr_scan(const int* __restrict__ deg, int* __restrict__ rowp,
                         float* __restrict__ dinvf, float* __restrict__ stats) {
  __shared__ int ps[1024];
  int t = threadIdx.x;
  if (t < 512) stats[t] = 0.0f;  // zero both shadow stat sets (2 x 256 floats)
  int base = t * 8;
  int loc[8];
  int s = 0;
  for (int j = 0; j < 8; j++) {
    int d = deg[base + j];
    loc[j] = s;
    s += d;
    dinvf[base + j] = rsqrtf((float)d + 1.0f);  // +1 self-loop
  }
  ps[t] = s;
  __syncthreads();
  for (int off = 1; off < 1024; off <<= 1) {
    int v = (t >= off) ? ps[t - off] : 0;
    __syncthreads();
    if (t >= off) ps[t] += v;
    __syncthreads();
  }
  int ex = (t > 0) ? ps[t - 1] : 0;
  for (int j = 0; j < 8; j++) rowp[base + j] = ex + loc[j];
  if (t == 1023) rowp[NN] = ex + s;
}

// ---------- role-split: [0,1024) csr_fill | [1024,2048) h0 = dinv*(x@W0) ----------
__global__ void fill_xw0(const int* __restrict__ esrc, const int* __restrict__ edst,
                         const int* __restrict__ rowp, int* __restrict__ cnt,
                         int* __restrict__ col, const void* __restrict__ X,
                         const void* __restrict__ W0, const float* __restrict__ dinvf,
                         const void* __restrict__ B, float* __restrict__ h0) {
  int bid = blockIdx.x, t = threadIdx.x;
  if (bid < 1024) {  // ---- CSR fill ----
    int e = bid * 256 + t;
    int d = edst[e];
    int pos = atomicAdd(&cnt[d], 1);
    col[rowp[d] + pos] = esrc[e];
    return;
  }
  // ---- gemm_x_w0 ----
  int isf = wave_detect(B);
  __shared__ float sW[FIN * HD];
  __shared__ float sx[8 * FIN];
  for (int i = t; i < FIN * HD; i += 256) sW[i] = ldin(W0, i, isf);
  int row0 = (bid - 1024) * 8;
  for (int i = t; i < 8 * FIN; i += 256) {
    int r = i >> 7, k = i & 127;
    sx[i] = ldin(X, (row0 + r) * FIN + k, isf);
  }
  __syncthreads();
  int r = t >> 5, c = t & 31;
  float acc = 0.f;
  for (int k = 0; k < FIN; k++) acc += sx[r * FIN + k] * sW[k * HD + c];
  h0[(row0 + r) * HD + c] = acc * dinvf[row0 + r];
}

// ---------- b1 = b @ Wa0 (MFMA, split-K x8 within one block, LDS reduce, plain store) ----
__global__ void gemm_b_wa0(const void* __restrict__ Bm, const unsigned short* __restrict__ Bp,
                           float* __restrict__ b1) {
  int isf = wave_detect(Bm);
  __shared__ float red[8][512];
  int t = threadIdx.x;  // 512 threads = 8 waves
  int kq = t >> 6;      // wave id = K-split
  int L = t & 63;
  int rt = blockIdx.x;  // 0..511 -> 16 rows each
  int q = L >> 4, n = L & 15;
  size_t aoff = (size_t)(rt * 16 + n) * NN + kq * 1024 + q * 8;
  f32x4 acc0 = {0.f, 0.f, 0.f, 0.f};
  f32x4 acc1 = {0.f, 0.f, 0.f, 0.f};
  int kb0 = kq * 32;
  if (isf) {
    const float* arow = (const float*)Bm + aoff;
    for (int i = 0; i < 32; i++) {
      f32x4 u0 = *(const f32x4*)(arow + i * 32);
      f32x4 u1 = *(const f32x4*)(arow + i * 32 + 4);
      union { unsigned short s[8]; short8 v; } au;
      au.s[0] = f2bf(u0[0]); au.s[1] = f2bf(u0[1]); au.s[2] = f2bf(u0[2]); au.s[3] = f2bf(u0[3]);
      au.s[4] = f2bf(u1[0]); au.s[5] = f2bf(u1[1]); au.s[6] = f2bf(u1[2]); au.s[7] = f2bf(u1[3]);
      const unsigned short* bpp = Bp + (size_t)((kb0 + i) * 2) * 512 + L * 8;
      acc0 = __builtin_amdgcn_mfma_f32_16x16x32_bf16(au.v, ld_bf8(bpp), acc0, 0, 0, 0);
      acc1 = __builtin_amdgcn_mfma_f32_16x16x32_bf16(au.v, ld_bf8(bpp + 512), acc1, 0, 0, 0);
    }
  } else {
    const unsigned short* arow = (const unsigned short*)Bm + aoff;
    for (int i = 0; i < 32; i++) {
      short8 a = ld_bf8(arow + i * 32);
      const unsigned short* bpp = Bp + (size_t)((kb0 + i) * 2) * 512 + L * 8;
      acc0 = __builtin_amdgcn_mfma_f32_16x16x32_bf16(a, ld_bf8(bpp), acc0, 0, 0, 0);
      acc1 = __builtin_amdgcn_mfma_f32_16x16x32_bf16(a, ld_bf8(bpp + 512), acc1, 0, 0, 0);
    }
  }
  for (int r = 0; r < 4; r++) {
    red[kq][(q * 4 + r) * 32 + n] = acc0[r];
    red[kq][(q * 4 + r) * 32 + n + 16] = acc1[r];
  }
  __syncthreads();
  float s = 0.f;
  for (int kw = 0; kw < 8; kw++) s += red[kw][t];
  b1[rt * 512 + t] = s;
}

// ---------- gather + fused BN stats: agg[d]=dinv[d]*(sum hs[s] + hs[d]); stats atomics --
// 2-deep independent accumulator chains per half-wave for memory-level parallelism.
// sums layout: [0..127] = 4 shadow sets of column sums, [128..255] = 4 shadow sq sets.
__global__ void gather_bn(const int* __restrict__ rowp, const int* __restrict__ col,
                          const float* __restrict__ dinvf, const float* __restrict__ hs,
                          float* __restrict__ agg, float* __restrict__ sums) {
  __shared__ float bs[32], bq[32];
  int t = threadIdx.x;
  if (t < 32) { bs[t] = 0.f; bq[t] = 0.f; }
  __syncthreads();
  int w = (blockIdx.x << 2) + (t >> 6);  // destination row
  int L = t & 63;
  int c = L & 31, half = L >> 5;
  int s0 = rowp[w], s1 = rowp[w + 1];
  float a0 = 0.f, a1 = 0.f;
  int e = s0 + half;
  for (; e + 2 < s1; e += 4) {  // edges e and e+2 in flight simultaneously
    int sA = col[e];
    int sB = col[e + 2];
    a0 += hs[sA * HD + c];
    a1 += hs[sB * HD + c];
  }
  if (e < s1) a0 += hs[col[e] * HD + c];
  float acc = a0 + a1;
  acc += __shfl_xor(acc, 32);
  if (half == 0) {
    float v = dinvf[w] * (acc + hs[w * HD + c]);  // + self-loop term
    agg[w * HD + c] = v;
    atomicAdd(&bs[c], v);
    atomicAdd(&bq[c], v * v);
  }
  __syncthreads();
  if (t < 32) {
    int sh = blockIdx.x & 3;  // 4 shadow sets cut global atomic contention 4x
    atomicAdd(&sums[sh * 32 + t], bs[t]);
    atomicAdd(&sums[128 + sh * 32 + t], bq[t]);
  }
}

// ---------- fused: bn_coef0 + x0=relu(BN(agg0)) + h1in=x0+b1+ba0 + hs1=dinv*(h1in@W1) ---
__global__ void fuse0_w1(float* __restrict__ aggA, const float* __restrict__ b1,
                         const void* __restrict__ ba0, const void* __restrict__ W1,
                         const float* __restrict__ st0,
                         const void* __restrict__ g0, const void* __restrict__ be0,
                         const float* __restrict__ dinvf, const void* __restrict__ B,
                         float* __restrict__ x0) {
  int isf = wave_detect(B);
  __shared__ float sW[1024], sh[16 * 33];
  int t = threadIdx.x;  // 512 threads
  for (int i = t; i < 1024; i += 512) sW[i] = ldin(W1, i, isf);
  int r = t >> 5, c = t & 31;
  int row = blockIdx.x * 16 + r;
  float ssum = st0[c] + st0[32 + c] + st0[64 + c] + st0[96 + c];
  float ssq = st0[128 + c] + st0[160 + c] + st0[192 + c] + st0[224 + c];
  float m = ssum * (1.0f / 8192.0f);
  float var = fmaxf(ssq * (1.0f / 8192.0f) - m * m, 0.0f);
  float ac = ldin(g0, c, isf) * rsqrtf(var + EPSBN);
  float bc = ldin(be0, c, isf) - m * ac;
  float v = aggA[row * HD + c];
  float xv = fmaxf(ac * v + bc, 0.0f);
  x0[row * HD + c] = xv;
  sh[r * 33 + c] = xv + b1[row * HD + c] + ldin(ba0, c, isf);
  __syncthreads();
  float acc = 0.f;
  for (int k = 0; k < 32; k++) acc += sh[r * 33 + k] * sW[k * HD + c];
  aggA[row * HD + c] = acc * dinvf[row];
}

// ---------- classifier (bn_coef1 inlined from shadows): log_softmax([x0 x1]@Wj+bj) ------
__global__ void classifier(const float* __restrict__ x0, const float* __restrict__ agg1,
                           const float* __restrict__ st1,
                           const void* __restrict__ g1, const void* __restrict__ be1,
                           const void* __restrict__ Wj, const void* __restrict__ bj,
                           const void* __restrict__ B, void* __restrict__ outv) {
  int isf = wave_detect(B);
  __shared__ float sW[64 * NC];
  __shared__ float sb[NC];
  __shared__ float sa[HD], sbb[HD];
  __shared__ float sx0[64 * 33], sx1[64 * 33];
  int t = threadIdx.x;  // 64 threads, one row each
  for (int i = t; i < 64 * NC; i += 64) sW[i] = ldin(Wj, i, isf);
  if (t < NC) sb[t] = ldin(bj, t, isf);
  if (t < HD) {
    float ssum = st1[t] + st1[32 + t] + st1[64 + t] + st1[96 + t];
    float ssq = st1[128 + t] + st1[160 + t] + st1[192 + t] + st1[224 + t];
    float m = ssum * (1.0f / 8192.0f);
    float var = fmaxf(ssq * (1.0f / 8192.0f) - m * m, 0.0f);
    float ac = ldin(g1, t, isf) * rsqrtf(var + EPSBN);
    sa[t] = ac;
    sbb[t] = ldin(be1, t, isf) - m * ac;
  }
  int row0 = blockIdx.x * 64;
  for (int i = t; i < 64 * HD; i += 64) {
    int r = i >> 5, k = i & 31;
    sx0[r * 33 + k] = x0[(size_t)row0 * HD + i];
    sx1[r * 33 + k] = agg1[(size_t)row0 * HD + i];
  }
  __syncthreads();
  float lg[NC];
  for (int c = 0; c < NC; c++) lg[c] = sb[c];
  for (int k = 0; k < HD; k++) {
    float v = sx0[t * 33 + k];
    for (int c = 0; c < NC; c++) lg[c] += v * sW[k * NC + c];
  }
  for (int k = 0; k < HD; k++) {
    float v = fmaxf(sa[k] * sx1[t * 33 + k] + sbb[k], 0.0f);  // BN+ReLU on the fly
    for (int c = 0; c < NC; c++) lg[c] += v * sW[(HD + k) * NC + c];
  }
  float mx = lg[0];
  for (int c = 1; c < NC; c++) mx = fmaxf(mx, lg[c]);
  float se = 0.f;
  for (int c = 0; c < NC; c++) se += expf(lg[c] - mx);
  float lse = mx + logf(se);
  int row = row0 + t;
  if (isf) {
    float* o = (float*)outv;
    for (int c = 0; c < NC; c++) o[row * NC + c] = lg[c] - lse;
  } else {
    unsigned short* o = (unsigned short*)outv;
    for (int c = 0; c < NC; c++) o[row * NC + c] = f2bf(lg[c] - lse);
  }
}

// ---------- out1 = (b1+ba0) @ M + r2. Operand-swapped MFMA -> 4 consecutive cols/lane
// -> one dwordx4 store per tile. Reads ONLY d_ws buffers + inputs. ----------
__global__ void gemm_b4(const float* __restrict__ b1, const void* __restrict__ ba0,
                        const unsigned short* __restrict__ Rp, const float* __restrict__ r2,
                        const void* __restrict__ B, void* __restrict__ outv) {
  int isf = wave_detect(B);
  int t = threadIdx.x;
  int w = (blockIdx.x << 2) + (t >> 6);
  int L = t & 63;
  int rt = w >> 3, jc = w & 7;
  int q = L >> 4, n = L & 15;
  // B-operand frag: B[k][n] = (b1+ba0)[row = rt*16+n][k = q*8+j]
  const float* ap = b1 + (size_t)(rt * 16 + n) * HD + q * 8;
  union { unsigned short s[8]; short8 v; } au;
  for (int j = 0; j < 8; j++) au.s[j] = f2bf(ap[j] + ldin(ba0, q * 8 + j, isf));
  short8 bfrag = au.v;
  int orow = rt * 16 + n;  // this lane's output row
  float* of = (float*)outv + NN * NC;
  unsigned short* ob = (unsigned short*)outv + NN * NC;
  for (int jt = jc * 64; jt < (jc + 1) * 64; jt++) {
    // A-operand frag: A[m][k] = M[k = q*8+j][col = jt*16 + n]  (same packed bytes)
    short8 afrag = ld_bf8(Rp + (size_t)(jt * 64 + L) * 8);
    f32x4 acc = {0.f, 0.f, 0.f, 0.f};
    acc = __builtin_amdgcn_mfma_f32_16x16x32_bf16(afrag, bfrag, acc, 0, 0, 0);
    int col = jt * 16 + q * 4;  // 4 consecutive columns per lane
    f32x4 radd = *(const f32x4*)(r2 + col);
    f32x4 res = acc + radd;
    size_t base = (size_t)orow * NN + col;
    if (isf) {
      *(f32x4*)(of + base) = res;
    } else {
      us4 pk;
      pk[0] = f2bf(res[0]); pk[1] = f2bf(res[1]); pk[2] = f2bf(res[2]); pk[3] = f2bf(res[3]);
      *(us4*)(ob + base) = pk;
    }
  }
}

extern "C" void kernel_launch(void* const* d_in, const int* in_sizes, int n_in,
                              void* d_out, int out_size, void* d_ws, size_t ws_size,
                              hipStream_t stream) {
  const void* B   = d_in[0];
  const void* X   = d_in[1];
  const int* EI   = (const int*)d_in[2];
  const void* W0  = d_in[3];
  const void* W1  = d_in[5];
  const void* g0  = d_in[7];
  const void* be0 = d_in[8];
  const void* g1  = d_in[9];
  const void* be1 = d_in[10];
  const void* Wa0 = d_in[11];
  const void* ba0 = d_in[12];
  const void* Wa1 = d_in[13];
  const void* ba1 = d_in[14];
  const void* Wa2 = d_in[15];
  const void* ba2 = d_in[16];
  const void* Wa3 = d_in[17];
  const void* ba3 = d_in[18];
  const void* Wj  = d_in[19];
  const void* bj  = d_in[20];
  (void)in_sizes; (void)n_in; (void)ws_size;

  const int* esrc = EI;
  const int* edst = EI + NE;

  // ---- d_ws layout: stats shadows + b1 + r2 + Rp (~1.6 MB) ----
  float* ws    = (float*)d_ws;
  float* stats = ws;                  // 512 floats: st0 [0..255], st1 [256..511]
  float* st0   = stats;
  float* st1   = stats + 256;
  float* b1    = stats + 512;         // NN*HD (fully written by gemm_b_wa0)
  float* r2    = b1 + NN * HD;        // NN
  unsigned short* Rp = (unsigned short*)(r2 + NN);  // 512*64*8 bf16 = 512 KB

  // ---- big scratch inside d_out's out1 region (overwritten by gemm_b4 last) ----
  size_t outBytesMin = (size_t)out_size * 2;
  size_t scratchBytes = (size_t)(NN + 3 * NN * HD) * 4        // degf + aggA + aggB + x0h
                      + (size_t)(256 * 2 * 64 * 8) * 2        // Bp
                      + (size_t)(3 * NN + 1 + NE) * 4;        // deg_i + cnt + rowp + col
  char* sc = (char*)d_out + ((outBytesMin - scratchBytes) & ~(size_t)255);
  float* degf = (float*)sc;           // NN   dinv values
  float* aggA = degf + NN;            // NN*HD (agg0 -> hs1 in place)
  float* aggB = aggA + NN * HD;       // NN*HD (agg1, BN'd on the fly in classifier)
  float* x0h  = aggB + NN * HD;       // NN*HD (hs0 -> x0)
  unsigned short* Bp = (unsigned short*)(x0h + NN * HD);  // 512 KB
  int* deg_i  = (int*)(Bp + 256 * 2 * 64 * 8);  // NN (zeroed by memset)
  int* cnt    = deg_i + NN;                     // NN (zeroed by memset)
  int* rowp   = cnt + NN;                       // NN+1
  int* col    = rowp + NN + 1;                  // NE

  hipMemsetAsync(deg_i, 0, (size_t)2 * NN * sizeof(int), stream);
  prep_all<<<1184, 256, 0, stream>>>(B, Wa1, ba1, Wa2, ba2, Wa3, ba3, Wa0,
                                     edst, deg_i, r2, Rp, Bp);
  csr_scan<<<1, 1024, 0, stream>>>(deg_i, rowp, degf, stats);
  fill_xw0<<<2048, 256, 0, stream>>>(esrc, edst, rowp, cnt, col, X, W0, degf, B, x0h);
  gemm_b_wa0<<<512, 512, 0, stream>>>(B, Bp, b1);
  gather_bn<<<NN / 4, 256, 0, stream>>>(rowp, col, degf, x0h, aggA, st0);      // agg0
  fuse0_w1<<<NN / 16, 512, 0, stream>>>(aggA, b1, ba0, W1, st0, g0, be0,
                                        degf, B, x0h);       // aggA<-hs1, x0h<-x0
  gather_bn<<<NN / 4, 256, 0, stream>>>(rowp, col, degf, aggA, aggB, st1);     // agg1
  classifier<<<NN / 64, 64, 0, stream>>>(x0h, aggB, st1, g1, be1, Wj, bj, B, d_out);
  gemm_b4<<<1024, 256, 0, stream>>>(b1, ba0, Rp, r2, B, d_out);  // overwrites all scratch
}